// Round 6
// baseline (416.768 us; speedup 1.0000x reference)
//
#include <hip/hip_runtime.h>
#include <hip/hip_bf16.h>
#include <stdint.h>

#define M_DIM 8192
#define N_DIM 4096
#define K_DIM 4096
#define NNZ   1600000

typedef __attribute__((ext_vector_type(8))) short bf16x8;
typedef __attribute__((ext_vector_type(16))) float f32x16;

// workspace layout (bytes)
static const size_t WF32_OFF  = 0;
static const size_t WBF16_OFF = 64ull << 20;
static const size_t XB_OFF    = 96ull << 20;
static const size_t WS_NEED   = 160ull << 20;

__device__ __forceinline__ unsigned short f2bf(float f) {
    union { float f; uint32_t u; } a; a.f = f;
    uint32_t u = a.u;
    uint32_t r = (u + 0x7FFFu + ((u >> 16) & 1u)) >> 16;   // RNE
    return (unsigned short)r;
}

__global__ void scatter_kernel(const int* __restrict__ idx,
                               const float* __restrict__ vals,
                               float* __restrict__ W) {
    int t = blockIdx.x * blockDim.x + threadIdx.x;
    if (t < NNZ) {
        int2 rc = ((const int2*)idx)[t];
        atomicAdd(&W[(size_t)rc.x * K_DIM + rc.y], vals[t]);
    }
}

__global__ void f32_to_bf16_kernel(const float* __restrict__ src,
                                   unsigned short* __restrict__ dst, int n4) {
    int t = blockIdx.x * blockDim.x + threadIdx.x;
    if (t < n4) {
        float4 v = ((const float4*)src)[t];
        ushort4 o;
        o.x = f2bf(v.x); o.y = f2bf(v.y); o.z = f2bf(v.z); o.w = f2bf(v.w);
        ((ushort4*)dst)[t] = o;
    }
}

// ---------------------------------------------------------------------------
// 256x256 bf16 MFMA GEMM, BK=64, 8 waves (2Mx4N), per-wave 128x64 out,
// mfma_f32_32x32x16_bf16 (matrix pipe at 2495 TF vs 2176 for 16x16; half the
// MFMA instruction count for the same LDS traffic).
// Per-wave decomposition: 4 m-subtiles (32 rows) x 2 n-subtiles (32 cols),
// K=64 as 4 kk-steps of 16. Phases are K-split so each 8-MFMA cluster has 4
// independent accumulator chains (dep distance 4):
//   ph0: read a(m01,kk01) 4 + b(n01,kk01) 4 | BAR | 8 MFMA | stage B(t+1)g23
//   ph1: read a(m23,kk01) 4                 | BAR | 8 MFMA |
//   ph2: read a(m01,kk23) 4 + b(n01,kk23) 4 | BAR | 8 MFMA | stage B(t+2)g01
//   ph3: read a(m23,kk23) 4                 | BAR | 8 MFMA | stage A(t+2)g0-3
//   boundary: vmcnt(6); BAR   (t==NT-2: vmcnt(0); t==NT-1: none)
// One barrier per phase (compiler interleaves adjacent phases' reads/MFMA —
// the r5 lever), counted vmcnt only (never 0 until tail).
// Stage safety: each staged region's last ds_read completed before the BAR
// preceding the stage-issue point (+ global-load latency margin).
// Fragment layouts: A/B row|col = lane&31, k = 8*(lane>>5)+i;
// C/D col = lane&31, row = (reg&3) + 8*(reg>>2) + 4*(lane>>5)  [m74/m101].
// LDS swizzle (0-conflict, measured r1-r5): 16B slot u of row r at u^(r&7);
// inverse-swizzled global source keeps gload_lds dest linear (rule 21).
// ---------------------------------------------------------------------------
#define GLOAD16(gp, lp) __builtin_amdgcn_global_load_lds( \
    (const __attribute__((address_space(1))) void*)(gp),  \
    (__attribute__((address_space(3))) void*)(lp), 16, 0, 0)
#define VMCNT(n)   asm volatile("s_waitcnt vmcnt(" #n ")" ::: "memory")
#define BAR()    __builtin_amdgcn_s_barrier()

// frag read from 256x64 swizzled tile: row r, 16-wide k-step kk in {0..3}
#define FRAG32(T, r, kk) \
    (*(const bf16x8*)&(T)[(r) * 64 + (((((kk) << 1) + l32) ^ ((r) & 7)) << 3)])

// stage one 64-row group g (0..3) of a 256x64 tile: 1 gload x 512 thr x 16B
#define STAGE_AG(buf, tt, g) \
    GLOAD16(Ab + (size_t)((g) * 64 + rbase) * K_DIM + (size_t)(tt) * 64 + cs, \
            &sA[buf][(g) * 4096 + wid * 512])
#define STAGE_BG(buf, tt, g) \
    GLOAD16(Bb + (size_t)((g) * 64 + rbase) * K_DIM + (size_t)(tt) * 64 + cs, \
            &sB[buf][(g) * 4096 + wid * 512])

__global__ __launch_bounds__(512, 2) void gemm256_v6(
        const __hip_bfloat16* __restrict__ A,   // M x K
        const __hip_bfloat16* __restrict__ B,   // N x K
        float* __restrict__ C)                  // M x N
{
    __shared__ __align__(16) __hip_bfloat16 sA[2][256 * 64];
    __shared__ __align__(16) __hip_bfloat16 sB[2][256 * 64];

    const int tid  = threadIdx.x;
    const int lane = tid & 63;
    const int wid  = tid >> 6;
    const int wr   = wid >> 2;      // 0..1  (128-row half of A-tile)
    const int wc   = wid & 3;       // 0..3  (64-col slice of B-tile)
    const int l31  = lane & 31, l32 = lane >> 5;

    // XCD-aware bijective swizzle (nwg = 512, %8 == 0)
    const int bid = blockIdx.x;
    const int swz = (bid & 7) * 64 + (bid >> 3);
    const int m0  = (swz >> 4) * 256;   // 32 m-tiles
    const int n0  = (swz & 15) * 256;   // 16 n-tiles

    // staging geometry: row-in-group = tid>>3; 16B col-slot u = tid&7;
    // inverse-swizzled source col = (u ^ (row&7))*8
    const int rbase = tid >> 3;
    const int cs    = ((tid & 7) ^ (rbase & 7)) << 3;

    const __hip_bfloat16* Ab = A + (size_t)m0 * K_DIM;
    const __hip_bfloat16* Bb = B + (size_t)n0 * K_DIM;

    f32x16 acc[4][2] = {};

    // ---- prologue: tile0 full (8), A(1) full (4), B(1) g0,g1 (2) ----
    STAGE_AG(0, 0, 0); STAGE_AG(0, 0, 1); STAGE_AG(0, 0, 2); STAGE_AG(0, 0, 3);
    STAGE_BG(0, 0, 0); STAGE_BG(0, 0, 1); STAGE_BG(0, 0, 2); STAGE_BG(0, 0, 3);
    STAGE_AG(1, 1, 0); STAGE_AG(1, 1, 1); STAGE_AG(1, 1, 2); STAGE_AG(1, 1, 3);
    STAGE_BG(1, 1, 0); STAGE_BG(1, 1, 1);
    VMCNT(6);          // tile 0 landed; {A(1) x4, B(1)g01 x2} in flight
    BAR();

    const int NT = K_DIM / 64;      // 64
    #pragma unroll 2
    for (int t = 0; t < NT; ++t) {
        const int c = t & 1;
        const __hip_bfloat16* TA = sA[c];
        const __hip_bfloat16* TB = sB[c];

        bf16x8 a01[2][2], a23[2][2], b01[2][2], b23[2][2];
        bf16x8 c01[2][2], c23[2][2];

        // ---------- phase 0: (m01 x n01) x kk{0,1} ----------
        #pragma unroll
        for (int m = 0; m < 2; ++m)
            #pragma unroll
            for (int k = 0; k < 2; ++k)
                a01[m][k] = FRAG32(TA, wr * 128 + m * 32 + l31, k);
        #pragma unroll
        for (int n = 0; n < 2; ++n)
            #pragma unroll
            for (int k = 0; k < 2; ++k)
                b01[n][k] = FRAG32(TB, wc * 64 + n * 32 + l31, k);
        BAR();
        __builtin_amdgcn_s_setprio(1);
        #pragma unroll
        for (int k = 0; k < 2; ++k)
            #pragma unroll
            for (int m = 0; m < 2; ++m)
                #pragma unroll
                for (int n = 0; n < 2; ++n)
                    acc[m][n] = __builtin_amdgcn_mfma_f32_32x32x16_bf16(
                                    a01[m][k], b01[n][k], acc[m][n], 0, 0, 0);
        __builtin_amdgcn_s_setprio(0);
        if (t + 1 < NT) { STAGE_BG(c ^ 1, t + 1, 2); STAGE_BG(c ^ 1, t + 1, 3); }

        // ---------- phase 1: (m23 x n01) x kk{0,1} ----------
        #pragma unroll
        for (int m = 0; m < 2; ++m)
            #pragma unroll
            for (int k = 0; k < 2; ++k)
                a23[m][k] = FRAG32(TA, wr * 128 + 64 + m * 32 + l31, k);
        BAR();
        __builtin_amdgcn_s_setprio(1);
        #pragma unroll
        for (int k = 0; k < 2; ++k)
            #pragma unroll
            for (int m = 0; m < 2; ++m)
                #pragma unroll
                for (int n = 0; n < 2; ++n)
                    acc[2 + m][n] = __builtin_amdgcn_mfma_f32_32x32x16_bf16(
                                    a23[m][k], b01[n][k], acc[2 + m][n], 0, 0, 0);
        __builtin_amdgcn_s_setprio(0);

        // ---------- phase 2: (m01 x n01) x kk{2,3} ----------
        #pragma unroll
        for (int m = 0; m < 2; ++m)
            #pragma unroll
            for (int k = 0; k < 2; ++k)
                c01[m][k] = FRAG32(TA, wr * 128 + m * 32 + l31, 2 + k);
        #pragma unroll
        for (int n = 0; n < 2; ++n)
            #pragma unroll
            for (int k = 0; k < 2; ++k)
                b23[n][k] = FRAG32(TB, wc * 64 + n * 32 + l31, 2 + k);
        BAR();
        __builtin_amdgcn_s_setprio(1);
        #pragma unroll
        for (int k = 0; k < 2; ++k)
            #pragma unroll
            for (int m = 0; m < 2; ++m)
                #pragma unroll
                for (int n = 0; n < 2; ++n)
                    acc[m][n] = __builtin_amdgcn_mfma_f32_32x32x16_bf16(
                                    c01[m][k], b23[n][k], acc[m][n], 0, 0, 0);
        __builtin_amdgcn_s_setprio(0);
        if (t + 2 < NT) { STAGE_BG(c, t + 2, 0); STAGE_BG(c, t + 2, 1); }

        // ---------- phase 3: (m23 x n01) x kk{2,3} ----------
        #pragma unroll
        for (int m = 0; m < 2; ++m)
            #pragma unroll
            for (int k = 0; k < 2; ++k)
                c23[m][k] = FRAG32(TA, wr * 128 + 64 + m * 32 + l31, 2 + k);
        BAR();
        __builtin_amdgcn_s_setprio(1);
        #pragma unroll
        for (int k = 0; k < 2; ++k)
            #pragma unroll
            for (int m = 0; m < 2; ++m)
                #pragma unroll
                for (int n = 0; n < 2; ++n)
                    acc[2 + m][n] = __builtin_amdgcn_mfma_f32_32x32x16_bf16(
                                    c23[m][k], b23[n][k], acc[2 + m][n], 0, 0, 0);
        __builtin_amdgcn_s_setprio(0);
        if (t + 2 < NT) {
            STAGE_AG(c, t + 2, 0); STAGE_AG(c, t + 2, 1);
            STAGE_AG(c, t + 2, 2); STAGE_AG(c, t + 2, 3);
        }

        // ---------- K-tile boundary ----------
        if (t < NT - 2) {
            VMCNT(6);       // drains tile t+1 fully; 6 loads of t+2 in flight
            BAR();
        } else if (t == NT - 2) {
            VMCNT(0);       // tail: drain B(NT-1)g2,g3
            BAR();
        }
        // t == NT-1: fall through to epilogue
    }

    // ---- epilogue: ReLU + fp32 store ----
    const int row_base = m0 + wr * 128;
    const int col_base = n0 + wc * 64;
    #pragma unroll
    for (int mi = 0; mi < 4; ++mi)
        #pragma unroll
        for (int ni = 0; ni < 2; ++ni) {
            const f32x16 v = acc[mi][ni];
            const int col = col_base + ni * 32 + l31;
            #pragma unroll
            for (int reg = 0; reg < 16; ++reg) {
                const int row = row_base + mi * 32 +
                                (reg & 3) + ((reg >> 2) << 3) + (l32 << 2);
                C[(size_t)row * N_DIM + col] = fmaxf(v[reg], 0.0f);
            }
        }
}

// ---------------------------------------------------------------------------
// fp32 fallback GEMM (only if ws_size < 160MB)
// ---------------------------------------------------------------------------
__global__ void gemm_f32_fallback(const float* __restrict__ A,
                                  const float* __restrict__ W,
                                  float* __restrict__ C) {
    __shared__ float As[64][17];
    __shared__ float Bs[64][17];
    const int tx = threadIdx.x & 15, ty = threadIdx.x >> 4;
    const int m0 = blockIdx.y * 64, n0 = blockIdx.x * 64;
    float acc[4][4] = {};
    for (int kt = 0; kt < K_DIM; kt += 16) {
        #pragma unroll
        for (int i = 0; i < 4; ++i) {
            int e = threadIdx.x + i * 256;
            int r = e >> 4, k = e & 15;
            As[r][k] = A[(size_t)(m0 + r) * K_DIM + kt + k];
            Bs[r][k] = W[(size_t)(n0 + r) * K_DIM + kt + k];
        }
        __syncthreads();
        #pragma unroll
        for (int k = 0; k < 16; ++k) {
            float av[4], bv[4];
            #pragma unroll
            for (int i = 0; i < 4; ++i) av[i] = As[ty * 4 + i][k];
            #pragma unroll
            for (int i = 0; i < 4; ++i) bv[i] = Bs[tx * 4 + i][k];
            #pragma unroll
            for (int i = 0; i < 4; ++i)
                #pragma unroll
                for (int j = 0; j < 4; ++j) acc[i][j] += av[i] * bv[j];
        }
        __syncthreads();
    }
    #pragma unroll
    for (int i = 0; i < 4; ++i)
        #pragma unroll
        for (int j = 0; j < 4; ++j)
            C[(size_t)(m0 + ty * 4 + i) * N_DIM + n0 + tx * 4 + j] =
                fmaxf(acc[i][j], 0.0f);
}

extern "C" void kernel_launch(void* const* d_in, const int* in_sizes, int n_in,
                              void* d_out, int out_size, void* d_ws, size_t ws_size,
                              hipStream_t stream) {
    const float* x       = (const float*)d_in[0];
    const int*   indices = (const int*)d_in[1];
    const float* values  = (const float*)d_in[2];
    float*       out     = (float*)d_out;

    float* Wf = (float*)((char*)d_ws + WF32_OFF);

    // 1. zero + scatter-build W (fp32, duplicates accumulate)
    hipMemsetAsync(Wf, 0, (size_t)N_DIM * K_DIM * sizeof(float), stream);
    scatter_kernel<<<(NNZ + 255) / 256, 256, 0, stream>>>(indices, values, Wf);

    if (ws_size >= WS_NEED) {
        unsigned short* Wb = (unsigned short*)((char*)d_ws + WBF16_OFF);
        unsigned short* xb = (unsigned short*)((char*)d_ws + XB_OFF);

        // 2. fp32 -> bf16 conversions
        {
            int n4 = (N_DIM * K_DIM) / 4;
            f32_to_bf16_kernel<<<(n4 + 255) / 256, 256, 0, stream>>>(Wf, Wb, n4);
        }
        {
            int n4 = (M_DIM * K_DIM) / 4;
            f32_to_bf16_kernel<<<(n4 + 255) / 256, 256, 0, stream>>>(x, xb, n4);
        }

        // 3. 256^2 4-phase 32x32x16 bf16 MFMA GEMM + ReLU
        gemm256_v6<<<(M_DIM / 256) * (N_DIM / 256), 512, 0, stream>>>(
            (const __hip_bfloat16*)xb, (const __hip_bfloat16*)Wb, out);
    } else {
        gemm_f32_fallback<<<dim3(N_DIM / 64, M_DIM / 64), 256, 0, stream>>>(
            x, Wf, out);
    }
}